// Round 6
// baseline (601.145 us; speedup 1.0000x reference)
//
#include <hip/hip_runtime.h>

// LogicVAE: graph-GRU VAE encoder. B=2048,N=32,V=10,H=256,Z=64.
// gm[b,n] = sigmoid(h@w_gate+b_gate)*(h@w_map) is a pure function of the FINAL
// hidden[b,n] (adj strictly upper-tri), so it's computed once per node.
// R6 vs R5 (487us kernel; nt gm loads = serialized HBM latency, FETCH stuck at
// 1.2GB): the WHOLE per-block gm slab (8x32x256 bf16 = 128KB) lives in dynamic
// LDS (gfx950 has 160KB/CU). Phase A = short ds_read chain; zero gm global
// traffic. aggbf/hnew shrunk to 8 rows (rows 8-15 are zero A-frags in regs).
// whh R-tile pinned in regs alongside gate tile (24KB/wave/step streamed).

#define BB 2048
#define NN 32
#define VV 10
#define HH 256
#define ZZ 64
#define BT 8      // batches per block
#define KC 8      // K chunks: 256/32
#define NT1 48    // 768/16 col tiles (w_hh)
#define NT2 32    // 512/16 col tiles (w_gate||w_map)
#define WHH_ELEMS (NT1 * KC * 64 * 8)             // 196608 ushorts
#define WGM_ELEMS (NT2 * KC * 64 * 8)             // 131072 ushorts
#define DYN_LDS_BYTES (BT * NN * HH * 2)          // 131072 B gm slab

typedef __attribute__((ext_vector_type(8))) short frag8;   // 8 bf16 (4 VGPR)
typedef __attribute__((ext_vector_type(4))) float facc4;   // MFMA accum

__device__ __forceinline__ float bf2f(unsigned short u) {
    unsigned int x = ((unsigned int)u) << 16;
    return __builtin_bit_cast(float, x);
}
__device__ __forceinline__ unsigned short f2bf(float f) {
    unsigned int x = __builtin_bit_cast(unsigned int, f);
    x += 0x7FFFu + ((x >> 16) & 1u);
    return (unsigned short)(x >> 16);
}
__device__ __forceinline__ float sigm(float x) { return 1.0f / (1.0f + __expf(-x)); }
__device__ __forceinline__ float ldv(const float* p, size_t i) { return p[i]; }
__device__ __forceinline__ float ldv(const unsigned short* p, size_t i) { return bf2f(p[i]); }
__device__ __forceinline__ void stv(float* p, size_t i, float v) { p[i] = v; }
__device__ __forceinline__ void stv(unsigned short* p, size_t i, float v) { p[i] = f2bf(v); }

// flag=1 => buffers are fp32, flag=0 => bf16. Integer-only tests (fast-math safe).
__global__ void detect_dtype(const unsigned short* __restrict__ w, int* flag) {
    __shared__ int zc, bc;
    if (threadIdx.x == 0) { zc = 0; bc = 0; }
    __syncthreads();
    int z = 0, b = 0;
    for (int i = threadIdx.x; i < 2048; i += 256) {
        unsigned short lo = w[2 * i];            // fp32: low mantissa half / bf16: a value
        if (lo == 0) z++;                        // bf16-rounded fp32 storage => all zero
        unsigned e = (lo >> 7) & 0xFFu;          // bf16 exponent field
        if (e >= 0x86u) b++;                     // |x|>=128 or NaN: impossible for N(0,.05) bf16
    }
    atomicAdd(&zc, z); atomicAdd(&bc, b);
    __syncthreads();
    if (threadIdx.x == 0) *flag = (bc > 0 || zc > 512) ? 1 : 0;
}

// Repack w_hh (256x768) and w_gate||w_map (256x512) into bf16 MFMA B-fragment
// order: frag f=jt*KC+kc; elem[(f*64+lane)*8+j] = W[kc*32+(lane>>4)*8+j][jt*16+(lane&15)]
template <typename T>
__global__ void repack_weights(const T* __restrict__ w_hh,
                               const T* __restrict__ w_gate,
                               const T* __restrict__ w_map,
                               unsigned short* __restrict__ whh_p,
                               unsigned short* __restrict__ wgm_p,
                               const int* __restrict__ flag, int want) {
    if (*flag != want) return;
    int t = blockIdx.x * blockDim.x + threadIdx.x;
    int lane = t & 63;
    int frag = t >> 6;                  // 0..639
    int kbase = (lane >> 4) * 8;
    if (frag < NT1 * KC) {
        int jt = frag / KC, kc = frag % KC;
        int col = jt * 16 + (lane & 15);
        unsigned short* dst = whh_p + ((size_t)frag * 64 + lane) * 8;
        #pragma unroll
        for (int j = 0; j < 8; ++j)
            dst[j] = f2bf(ldv(w_hh, (size_t)(kc * 32 + kbase + j) * 768 + col));
    } else if (frag < (NT1 + NT2) * KC) {
        int f2 = frag - NT1 * KC;
        int jt = f2 / KC, kc = f2 % KC;
        int col = jt * 16 + (lane & 15);
        unsigned short* dst = wgm_p + ((size_t)f2 * 64 + lane) * 8;
        #pragma unroll
        for (int j = 0; j < 8; ++j) {
            int k = kc * 32 + kbase + j;
            dst[j] = f2bf((col < HH) ? ldv(w_gate, (size_t)k * HH + col)
                                     : ldv(w_map, (size_t)k * HH + (col - HH)));
        }
    }
}

template <typename T>
__global__ __launch_bounds__(1024, 4) void vae_main(
    const T* __restrict__ adj,
    const int* __restrict__ ntypes,
    const T* __restrict__ w_ih,
    const T* __restrict__ b_ih,
    const T* __restrict__ b_hh,
    const T* __restrict__ b_gate,
    const T* __restrict__ w_mu,
    const T* __restrict__ b_mu,
    const T* __restrict__ w_std,
    const T* __restrict__ b_std,
    const unsigned short* __restrict__ whh_p,
    const unsigned short* __restrict__ wgm_p,
    T* __restrict__ out,
    const int* __restrict__ flag, int want)
{
    if (*flag != want) return;

    extern __shared__ __align__(16) char dyn_lds[];
    unsigned short* gmS = (unsigned short*)dyn_lds;         // [BT][NN][HH] 128 KB

    __shared__ __align__(16) float agg[BT][HH];             // fp32 agg (8 KB)
    __shared__ __align__(16) unsigned short aggbf[BT][264]; // MFMA A rows 0-7 (4.2 KB)
    __shared__ __align__(16) unsigned short hnew[BT][264];  // MFMA A rows 0-7 (4.2 KB)
    __shared__ unsigned int  amask[BT][NN];                 // adj bitmasks (1 KB)
    __shared__ int           ntva[BT][NN];                  // node types (1 KB)
    __shared__ unsigned short bihL[768], bhhL[768], bgL[HH]; // biases bf16 (3.5 KB)

    const int tid  = threadIdx.x;
    const int lane = tid & 63;
    const int w    = tid >> 6;          // wave 0..15
    const int b0   = blockIdx.x * BT;

    const frag8* whh8 = (const frag8*)whh_p;
    const frag8* wgm8 = (const frag8*)wgm_p;

    // ---- one-time preload ----
    if (tid < 256) {                         // adj -> bitmask (adj is exactly {0,1})
        int bi = tid >> 5, vv = tid & 31;
        unsigned m = 0;
        for (int n = 0; n < NN; ++n)
            if (ldv(adj, ((size_t)(b0 + bi) * NN + n) * NN + vv) != 0.0f) m |= (1u << n);
        amask[bi][vv] = m;
    } else if (tid < 512) {
        int idx = tid - 256;
        int bi = idx >> 5, vv = idx & 31;
        ntva[bi][vv] = ntypes[(b0 + bi) * NN + vv];
    }
    for (int i = tid; i < 768; i += 1024) {
        bihL[i] = f2bf(ldv(b_ih, i));
        bhhL[i] = f2bf(ldv(b_hh, i));
    }
    if (tid < HH) bgL[tid] = f2bf(ldv(b_gate, tid));

    // ---- pin per-wave weight tiles in regs: whh R-tile (t) + wgm gate tile (t)
    frag8 wR[KC], wG[KC];
    {
        const frag8* pR = whh8 + (size_t)w * (KC * 64) + lane;
        const frag8* pG = wgm8 + (size_t)w * (KC * 64) + lane;
        #pragma unroll
        for (int kc = 0; kc < KC; ++kc) { wR[kc] = pR[kc * 64]; wG[kc] = pG[kc * 64]; }
    }
    __syncthreads();

    const int arow  = lane & 15;
    const int acol0 = (lane >> 4) * 8;

    for (int v = 0; v < NN; ++v) {
        // ---- A (waves 0..7): agg[bi][:] = sum over set bits of gm LDS rows
        if (w < BT) {
            const int bi = w;
            const int h4 = lane * 4;
            const unsigned short* rb = gmS + (size_t)(bi * NN) * HH + h4;
            unsigned m = amask[bi][v];       // wave-uniform
            float a0 = 0.f, a1 = 0.f, a2 = 0.f, a3 = 0.f;
            float c0 = 0.f, c1 = 0.f, c2 = 0.f, c3 = 0.f;
            while (m) {                      // 2-wide unrolled edge walk (ILP)
                int n0 = __builtin_ctz(m); m &= m - 1;
                const ushort4 g0 = *(const ushort4*)(rb + n0 * HH);
                if (m) {
                    int n1 = __builtin_ctz(m); m &= m - 1;
                    const ushort4 g1 = *(const ushort4*)(rb + n1 * HH);
                    c0 += bf2f(g1.x); c1 += bf2f(g1.y);
                    c2 += bf2f(g1.z); c3 += bf2f(g1.w);
                }
                a0 += bf2f(g0.x); a1 += bf2f(g0.y);
                a2 += bf2f(g0.z); a3 += bf2f(g0.w);
            }
            a0 += c0; a1 += c1; a2 += c2; a3 += c3;
            *(float4*)&agg[bi][h4] = make_float4(a0, a1, a2, a3);
            ushort4 ab; ab.x = f2bf(a0); ab.y = f2bf(a1); ab.z = f2bf(a2); ab.w = f2bf(a3);
            *(ushort4*)&aggbf[bi][h4] = ab;
        }
        __syncthreads();

        // ---- B: gh = agg @ w_hh (MFMA) fused with GRU elementwise -> hnew
        {
            frag8 afrag[KC];
            if (arow < BT) {
                #pragma unroll
                for (int kc = 0; kc < KC; ++kc)
                    afrag[kc] = *(const frag8*)&aggbf[arow][kc * 32 + acol0];
            } else {
                #pragma unroll
                for (int kc = 0; kc < KC; ++kc) afrag[kc] = frag8{};
            }

            const int t = w;                             // triplet: cols t, t+16, t+32
            facc4 aR = {0.f, 0.f, 0.f, 0.f};
            facc4 aZ = {0.f, 0.f, 0.f, 0.f};
            facc4 aN = {0.f, 0.f, 0.f, 0.f};
            const frag8* pZ = whh8 + (size_t)(t + 16) * (KC * 64) + lane;
            const frag8* pN = whh8 + (size_t)(t + 32) * (KC * 64) + lane;
            #pragma unroll
            for (int kc = 0; kc < KC; ++kc) {
                aR = __builtin_amdgcn_mfma_f32_16x16x32_bf16(afrag[kc], wR[kc], aR, 0, 0, 0);
                aZ = __builtin_amdgcn_mfma_f32_16x16x32_bf16(afrag[kc], pZ[kc * 64], aZ, 0, 0, 0);
                aN = __builtin_amdgcn_mfma_f32_16x16x32_bf16(afrag[kc], pN[kc * 64], aN, 0, 0, 0);
            }
            const int col = t * 16 + (lane & 15);
            const int q = lane >> 4;                     // C row = 4q+i, valid q<2
            if (q < 2) {
                const float bir  = bf2f(bihL[col]),       bhr = bf2f(bhhL[col]);
                const float biz  = bf2f(bihL[col + 256]), bhz = bf2f(bhhL[col + 256]);
                const float bin_ = bf2f(bihL[col + 512]), bhn = bf2f(bhhL[col + 512]);
                #pragma unroll
                for (int i = 0; i < 4; ++i) {
                    const int bi = 4 * q + i;
                    const size_t ty = (size_t)ntva[bi][v] * 768;
                    const float xr = ldv(w_ih, ty + col);
                    const float xz = ldv(w_ih, ty + col + 256);
                    const float xn = ldv(w_ih, ty + col + 512);
                    const float r = sigm(xr + bir + aR[i] + bhr);
                    const float z = sigm(xz + biz + aZ[i] + bhz);
                    const float n = tanhf(xn + bin_ + r * (aN[i] + bhn));
                    const float h = (1.f - z) * n + z * agg[bi][col];
                    hnew[bi][col] = f2bf(h);
                }
            }
        }
        __syncthreads();

        // ---- D: gm_v = sigmoid(h@w_gate+b_gate) * (h@w_map) -> gm slab (LDS)
        {
            frag8 hfrag[KC];
            if (arow < BT) {
                #pragma unroll
                for (int kc = 0; kc < KC; ++kc)
                    hfrag[kc] = *(const frag8*)&hnew[arow][kc * 32 + acol0];
            } else {
                #pragma unroll
                for (int kc = 0; kc < KC; ++kc) hfrag[kc] = frag8{};
            }

            const int t = w;                             // gate tile t (pinned), map t+16
            facc4 aG = {0.f, 0.f, 0.f, 0.f};
            facc4 aM = {0.f, 0.f, 0.f, 0.f};
            const frag8* pM = wgm8 + (size_t)(t + 16) * (KC * 64) + lane;
            #pragma unroll
            for (int kc = 0; kc < KC; ++kc) {
                aG = __builtin_amdgcn_mfma_f32_16x16x32_bf16(hfrag[kc], wG[kc], aG, 0, 0, 0);
                aM = __builtin_amdgcn_mfma_f32_16x16x32_bf16(hfrag[kc], pM[kc * 64], aM, 0, 0, 0);
            }
            const int col = t * 16 + (lane & 15);        // 0..255
            const int q = lane >> 4;
            if (q < 2) {
                const float bg = bf2f(bgL[col]);
                #pragma unroll
                for (int i = 0; i < 4; ++i) {
                    const int bi = 4 * q + i;
                    gmS[(size_t)(bi * NN + v) * HH + col] = f2bf(sigm(aG[i] + bg) * aM[i]);
                }
            }
        }
        __syncthreads();   // gm row v / hnew ready for next step / epilogue
    }

    // ---- Epilogue: hg = h_new(v=31) (in hnew LDS); mu/sigma = hg@w_mu/std + b
    {
        const int bi = w >> 1, half = w & 1, z = lane;   // 2 waves per batch
        float am = 0.f, as = 0.f;
        const int h0 = half * 128;
        #pragma unroll 4
        for (int h = h0; h < h0 + 128; ++h) {
            const float hv = bf2f(hnew[bi][h]);          // LDS broadcast
            am += hv * ldv(w_mu, (size_t)h * ZZ + z);
            as += hv * ldv(w_std, (size_t)h * ZZ + z);
        }
        agg[bi][half * 64 + z]       = am;               // agg LDS reused as scratch
        agg[bi][128 + half * 64 + z] = as;
    }
    __syncthreads();
    if (w < BT) {
        const int bi = w, z = lane;
        const float am = agg[bi][z] + agg[bi][64 + z] + ldv(b_mu, z);
        const float as = agg[bi][128 + z] + agg[bi][192 + z] + ldv(b_std, z);
        stv(out, (size_t)(b0 + bi) * ZZ + z, am);
        stv(out, (size_t)BB * ZZ + (size_t)(b0 + bi) * ZZ + z, as);
    }
}

extern "C" void kernel_launch(void* const* d_in, const int* in_sizes, int n_in,
                              void* d_out, int out_size, void* d_ws, size_t ws_size,
                              hipStream_t stream)
{
    unsigned short* whh_p = (unsigned short*)d_ws;
    unsigned short* wgm_p = whh_p + WHH_ELEMS;

    // dtype flag lives in the last aligned 4 bytes of ws
    size_t flag_off = (ws_size >= 8) ? ((ws_size - 4) & ~(size_t)3) : 0;
    int* flag = (int*)((char*)d_ws + flag_off);

    // allow >64KB dynamic LDS (gfx950: 160KB/CU). Host-side, capture-safe.
    (void)hipFuncSetAttribute(reinterpret_cast<const void*>(&vae_main<float>),
                              hipFuncAttributeMaxDynamicSharedMemorySize, DYN_LDS_BYTES);
    (void)hipFuncSetAttribute(reinterpret_cast<const void*>(&vae_main<unsigned short>),
                              hipFuncAttributeMaxDynamicSharedMemorySize, DYN_LDS_BYTES);

    detect_dtype<<<dim3(1), 256, 0, stream>>>((const unsigned short*)d_in[2], flag);

    repack_weights<float><<<dim3(160), 256, 0, stream>>>(
        (const float*)d_in[3], (const float*)d_in[6], (const float*)d_in[8],
        whh_p, wgm_p, flag, 1);
    repack_weights<unsigned short><<<dim3(160), 256, 0, stream>>>(
        (const unsigned short*)d_in[3], (const unsigned short*)d_in[6],
        (const unsigned short*)d_in[8], whh_p, wgm_p, flag, 0);

    vae_main<float><<<dim3(BB / BT), 1024, DYN_LDS_BYTES, stream>>>(
        (const float*)d_in[0], (const int*)d_in[1], (const float*)d_in[2],
        (const float*)d_in[4], (const float*)d_in[5], (const float*)d_in[7],
        (const float*)d_in[9], (const float*)d_in[10], (const float*)d_in[11],
        (const float*)d_in[12], whh_p, wgm_p, (float*)d_out, flag, 1);
    vae_main<unsigned short><<<dim3(BB / BT), 1024, DYN_LDS_BYTES, stream>>>(
        (const unsigned short*)d_in[0], (const int*)d_in[1],
        (const unsigned short*)d_in[2], (const unsigned short*)d_in[4],
        (const unsigned short*)d_in[5], (const unsigned short*)d_in[7],
        (const unsigned short*)d_in[9], (const unsigned short*)d_in[10],
        (const unsigned short*)d_in[11], (const unsigned short*)d_in[12],
        whh_p, wgm_p, (unsigned short*)d_out, flag, 0);
}